// Round 6
// baseline (293.943 us; speedup 1.0000x reference)
//
#include <hip/hip_runtime.h>
#include <hip/hip_bf16.h>
#include <math.h>

typedef __attribute__((ext_vector_type(8))) short short8;
typedef __attribute__((ext_vector_type(4))) float floatx4;
typedef __attribute__((ext_vector_type(4))) unsigned int uintx4;
typedef __attribute__((ext_vector_type(2))) unsigned int uintx2;

__device__ __forceinline__ unsigned short f2bf(float f) {
    unsigned int u = __float_as_uint(f);
    unsigned int r = (u + 0x7fffu + ((u >> 16) & 1u)) >> 16;
    return (unsigned short)r;
}

__device__ __forceinline__ unsigned int pk2bf(float a, float b) {
    unsigned int ua = __float_as_uint(a);
    ua = ua + 0x7fffu + ((ua >> 16) & 1u);
    unsigned int ub = __float_as_uint(b);
    ub = ub + 0x7fffu + ((ub >> 16) & 1u);
    return (ua >> 16) | (ub & 0xffff0000u);
}

// tanh-gelu via u*sigmoid(y), y=1.59577*u*(1+0.044715u^2), Schraudolph fast exp
__device__ __forceinline__ float gelu_f(float u) {
    float u2 = u * u;
    float y = u * fmaf(u2, 0.0713548163f, 1.5957691216f);
    y = fminf(fmaxf(y, -87.0f), 87.0f);
    float f = fmaf(y, -12102203.16f, 1064866805.0f);   // bits of e^{-y}
    float e = __int_as_float((int)f);
    return u * __builtin_amdgcn_rcpf(1.0f + e);
}

__device__ __forceinline__ floatx4 mfma16(short8 a, short8 b, floatx4 c) {
    return __builtin_amdgcn_mfma_f32_16x16x32_bf16(a, b, c, 0, 0, 0);
}

// ---------------- Phase A ----------------

// 512 blocks: deterministic partial |W| sums (16 partials per tile)
__global__ __launch_bounds__(256) void k_sumabs(const float* __restrict__ W1,
                                                const float* __restrict__ W2,
                                                float* __restrict__ partials) {
    int blk = blockIdx.x;
    bool isW1 = blk < 256;
    const float* W = (isW1 ? W1 : W2) + (long)(isW1 ? blk : blk - 256) * 4096;
    float s = 0.f;
    #pragma unroll
    for (int i = 0; i < 4; i++) {
        floatx4 v = *(const floatx4*)(W + i * 1024 + threadIdx.x * 4);
        s += fabsf(v[0]) + fabsf(v[1]) + fabsf(v[2]) + fabsf(v[3]);
    }
    __shared__ float red[256];
    red[threadIdx.x] = s; __syncthreads();
    for (int st = 128; st > 0; st >>= 1) {
        if (threadIdx.x < st) red[threadIdx.x] += red[threadIdx.x + st];
        __syncthreads();
    }
    if (threadIdx.x == 0) partials[blk] = red[0];
}

// blocks 0..127: W1 quant+transpose via LDS tile (coalesced both sides)
// blocks 128..383: W2 quant straight (layout [n][d] kept for k_w23)
__global__ __launch_bounds__(256) void k_quant(
        const float* __restrict__ W1, const float* __restrict__ W2,
        const float* __restrict__ partials,
        unsigned short* __restrict__ W1qT, unsigned short* __restrict__ W2q,
        float* ternsum) {
    __shared__ unsigned short lt[64 * 136];   // transpose tile
    __shared__ float red[256];
    int blk = blockIdx.x;
    int tid = threadIdx.x;
    float dsum = 0.f;

    if (blk < 128) {
        int t = blk >> 3, n0 = (blk & 7) * 64;
        const float* part = partials + t * 16;
        float ssum = 0.f;
        #pragma unroll
        for (int i = 0; i < 16; i++) ssum += part[i];
        float s = ssum * (1.0f / 65536.0f);
        float thr = 0.7f * s;
        const float* Wt = W1 + (long)t * 65536;
        int j = tid & 63, dbase = tid >> 6;
        #pragma unroll 4
        for (int i = 0; i < 32; i++) {
            int d = i * 4 + dbase;
            float w = Wt[d * 512 + n0 + j];
            float q = (fabsf(w) > thr) ? (w > 0.f ? s : -s) : 0.f;
            dsum += fabsf(w - q);
            lt[j * 136 + d] = f2bf(q);
        }
        __syncthreads();
        int n = tid >> 2, qd = (tid & 3) * 32;
        unsigned short* dst = W1qT + (long)t * 65536 + (n0 + n) * 128 + qd;
        const unsigned short* srcr = lt + n * 136 + qd;
        #pragma unroll
        for (int p = 0; p < 4; p++)
            *(uintx4*)(dst + p * 8) = *(const uintx4*)(srcr + p * 8);
    } else {
        int idx = blk - 128;
        long el0 = (long)idx * 4096;
        int t = (int)(el0 >> 16);
        const float* part = partials + 256 + t * 16;
        float ssum = 0.f;
        #pragma unroll
        for (int i = 0; i < 16; i++) ssum += part[i];
        float s = ssum * (1.0f / 65536.0f);
        float thr = 0.7f * s;
        const float* src = W2 + el0;
        unsigned short* dst = W2q + el0;
        #pragma unroll
        for (int i = 0; i < 4; i++) {
            int off = i * 1024 + tid * 4;
            floatx4 w = *(const floatx4*)(src + off);
            floatx4 q;
            #pragma unroll
            for (int r = 0; r < 4; r++) {
                q[r] = (fabsf(w[r]) > thr) ? (w[r] > 0.f ? s : -s) : 0.f;
                dsum += fabsf(w[r] - q[r]);
            }
            uintx2 o; o[0] = pk2bf(q[0], q[1]); o[1] = pk2bf(q[2], q[3]);
            *(uintx2*)(dst + off) = o;
        }
    }
    red[tid] = dsum; __syncthreads();
    for (int st2 = 128; st2 > 0; st2 >>= 1) {
        if (tid < st2) red[tid] += red[tid + st2];
        __syncthreads();
    }
    if (tid == 0) atomicAdd(ternsum, red[0]);
}

__global__ void k_tables(const float* __restrict__ op_embed, const float* __restrict__ W_in,
                         const float* __restrict__ b_in, const float* __restrict__ Wh1,
                         float* embW, float* Ta, float* Tb, float* Tc,
                         unsigned short* Wh1T) {
    int i = blockIdx.x * 256 + threadIdx.x;
    if (i < 1024) {
        int op = i >> 7, j = i & 127;
        float s = b_in[j];
        #pragma unroll
        for (int k = 0; k < 32; k++) s += op_embed[op * 32 + k] * W_in[k * 128 + j];
        embW[i] = s;
    } else if (i < 1024 + 32768) {
        int r = i - 1024; int a = r >> 7, j = r & 127;
        float s = 0.f;
        #pragma unroll
        for (int bit = 0; bit < 8; bit++) if ((a >> bit) & 1) s += W_in[(32 + bit) * 128 + j];
        Ta[r] = s;
    } else if (i < 33792 + 32768) {
        int r = i - 33792; int b = r >> 7, j = r & 127;
        float s = 0.f;
        #pragma unroll
        for (int bit = 0; bit < 8; bit++) if ((b >> bit) & 1) s += W_in[(40 + bit) * 128 + j];
        Tb[r] = s;
    } else if (i < 66560 + 128) {
        int j = i - 66560; Tc[j] = W_in[48 * 128 + j];
    } else if (i < 66688 + 8192) {
        int r = i - 66688; int h = r >> 7, k = r & 127;
        Wh1T[r] = f2bf(Wh1[k * 64 + h]);
    }
}

__global__ void k_tablesR(const float* __restrict__ embW, const float* __restrict__ Ta,
                          const float* __restrict__ Tb, const float* __restrict__ Tc,
                          const float* __restrict__ Wr,
                          float* embWr, float* TaR, float* TbR, float* TcR) {
    int i = blockIdx.x * 256 + threadIdx.x;
    int row = i >> 4, t = i & 15;
    const float* src; float* dst;
    if (row < 8)        { src = embW + row * 128;        dst = embWr + i; }
    else if (row < 264) { src = Ta + (row - 8) * 128;    dst = TaR + (row - 8) * 16 + t; }
    else if (row < 520) { src = Tb + (row - 264) * 128;  dst = TbR + (row - 264) * 16 + t; }
    else if (row == 520){ src = Tc;                      dst = TcR + t; }
    else return;
    float s = 0.f;
    for (int j = 0; j < 128; j++) s += src[j] * Wr[j * 16 + t];
    *dst = s;
}

// W23qT[t][h][k2] = (W2q[t] @ Wh1)^T via MFMA: A=Wh1T rows, B=W2q rows (global)
__global__ __launch_bounds__(256) void k_w23(
        const unsigned short* __restrict__ W2q, const unsigned short* __restrict__ Wh1T,
        unsigned short* __restrict__ W23qT) {
    int t = blockIdx.x >> 3, n0 = (blockIdx.x & 7) * 64;
    int tid = threadIdx.x;
    int lane = tid & 63, w = tid >> 6;
    int lane15 = lane & 15, lgrp = lane >> 4;
    const unsigned short* bp = W2q + (long)t * 65536 + (n0 + w * 16 + lane15) * 128 + lgrp * 8;
    floatx4 acc[4];
    #pragma unroll
    for (int i = 0; i < 4; i++) acc[i] = (floatx4){0.f, 0.f, 0.f, 0.f};
    #pragma unroll
    for (int kk = 0; kk < 4; kk++) {
        short8 bf = *(const short8*)(bp + kk * 32);
        #pragma unroll
        for (int ht = 0; ht < 4; ht++) {
            short8 af = *(const short8*)(Wh1T + (ht * 16 + lane15) * 128 + lgrp * 8 + kk * 32);
            acc[ht] = mfma16(af, bf, acc[ht]);
        }
    }
    int n = n0 + w * 16 + lane15;
    #pragma unroll
    for (int ht = 0; ht < 4; ht++) {
        #pragma unroll
        for (int r = 0; r < 4; r++) {
            int h = ht * 16 + lgrp * 4 + r;
            W23qT[((long)t * 64 + h) * 512 + n] = f2bf(acc[ht][r]);
        }
    }
}

// ---------------- Phase B: router + x ----------------

__global__ __launch_bounds__(256) void k_front(
        const int* __restrict__ op_idx, const int* __restrict__ a_in,
        const int* __restrict__ b_in_i, const int* __restrict__ c_in,
        const float* __restrict__ embW, const float* __restrict__ Ta,
        const float* __restrict__ Tb, const float* __restrict__ Tc,
        const float* __restrict__ embWr, const float* __restrict__ TaR,
        const float* __restrict__ TbR, const float* __restrict__ TcR,
        unsigned short* __restrict__ xq, float* __restrict__ gate_out,
        float* psum, int* cnt, float* __restrict__ d_idx) {
    __shared__ float sp[4][16];
    __shared__ int sc[4][16];
    int gid = blockIdx.x * 256 + threadIdx.x;
    int lane = threadIdx.x & 63;
    int j = lane & 15;
    int grpbase = lane & 48;
    float psum_acc = 0.f; int cnt_acc = 0;

    #pragma unroll 1
    for (int it = 0; it < 16; it++) {
        int tok = it * 16384 + (gid >> 4);
        int op = op_idx[tok], a = a_in[tok], b = b_in_i[tok], c = c_in[tok];
        float cf = (float)c;

        float lg = embWr[op * 16 + j] + TaR[a * 16 + j] + TbR[b * 16 + j] + cf * TcR[j];
        float m = lg;
        m = fmaxf(m, __shfl_xor(m, 8, 16));
        m = fmaxf(m, __shfl_xor(m, 4, 16));
        m = fmaxf(m, __shfl_xor(m, 2, 16));
        m = fmaxf(m, __shfl_xor(m, 1, 16));
        float p = __expf(lg - m);
        float s = p;
        s += __shfl_xor(s, 8, 16);
        s += __shfl_xor(s, 4, 16);
        s += __shfl_xor(s, 2, 16);
        s += __shfl_xor(s, 1, 16);
        float g = __builtin_amdgcn_rcpf(s);
        unsigned long long ball = __ballot(lg == m);
        int bi = __ffsll((unsigned long long)((ball >> grpbase) & 0xffffULL)) - 1;
        psum_acc += p * g;
        cnt_acc += (j == bi) ? 1 : 0;
        if (j == 0) { gate_out[tok] = g; d_idx[tok] = (float)bi; }

        int d0 = j * 8;
        const floatx4* E  = (const floatx4*)(embW + op * 128 + d0);
        const floatx4* A4 = (const floatx4*)(Ta + a * 128 + d0);
        const floatx4* B4 = (const floatx4*)(Tb + b * 128 + d0);
        const floatx4* C4 = (const floatx4*)(Tc + d0);
        floatx4 v0 = E[0] + A4[0] + B4[0] + cf * C4[0];
        floatx4 v1 = E[1] + A4[1] + B4[1] + cf * C4[1];
        uintx4 o;
        o[0] = pk2bf(v0[0], v0[1]);
        o[1] = pk2bf(v0[2], v0[3]);
        o[2] = pk2bf(v1[0], v1[1]);
        o[3] = pk2bf(v1[2], v1[3]);
        *(uintx4*)(xq + (long)tok * 128 + d0) = o;
    }

    psum_acc += __shfl_xor(psum_acc, 16);
    psum_acc += __shfl_xor(psum_acc, 32);
    cnt_acc += __shfl_xor(cnt_acc, 16);
    cnt_acc += __shfl_xor(cnt_acc, 32);
    int wv = threadIdx.x >> 6;
    if (lane < 16) { sp[wv][j] = psum_acc; sc[wv][j] = cnt_acc; }
    __syncthreads();
    if (threadIdx.x < 16) {
        int jj = threadIdx.x;
        atomicAdd(&psum[jj], sp[0][jj] + sp[1][jj] + sp[2][jj] + sp[3][jj]);
        atomicAdd(&cnt[jj], sc[0][jj] + sc[1][jj] + sc[2][jj] + sc[3][jj]);
    }
}

// ---------------- scatter: packed {tok, gate} records ----------------

__global__ void k_scatter(const float* __restrict__ d_idx, const float* __restrict__ gate,
                          const int* __restrict__ cnt,
                          int* fill, uintx2* __restrict__ records) {
    __shared__ int lc[16], lbase[16];
    if (threadIdx.x < 16) lc[threadIdx.x] = 0;
    __syncthreads();
    int offs[16];
    {
        int off = 0;
        #pragma unroll
        for (int tt = 0; tt < 16; tt++) { offs[tt] = off; off += cnt[tt]; }
    }
    int tok = blockIdx.x * 256 + threadIdx.x;
    int t = (int)d_idx[tok];
    int lpos = atomicAdd(&lc[t], 1);
    __syncthreads();
    if (threadIdx.x < 16) lbase[threadIdx.x] = atomicAdd(&fill[threadIdx.x], lc[threadIdx.x]);
    __syncthreads();
    uintx2 rec;
    rec[0] = (unsigned)tok;
    rec[1] = __float_as_uint(gate[tok]);
    records[offs[t] + lbase[t] + lpos] = rec;
}

// ---------------- Phase C: MoE FFN + fused head ----------------
// X B-fragments cached in VGPRs; Pb overlays the X LDS buffer; GEMM1 is LDS-free.

__global__ __launch_bounds__(256, 4) void k_ffn(
    const unsigned short* __restrict__ xq, const uintx2* __restrict__ recs,
    const int* __restrict__ cnt_g,
    const float* __restrict__ psum_g, const float* __restrict__ ternsum_g,
    const unsigned short* __restrict__ W1qT, const unsigned short* __restrict__ W23qT,
    const float* __restrict__ Wh2, const float* __restrict__ bh1,
    const float* __restrict__ bh2,
    float* __restrict__ result, float* __restrict__ d_aux) {

    extern __shared__ __align__(16) unsigned char smem[];
    unsigned short* XP = (unsigned short*)smem;        // [64][136] bf16: X -> P -> H(f32 [64][68])
    int*   toks = (int*)(smem + 17408);
    float* gats = (float*)(smem + 17664);
    float* Wh2l = (float*)(smem + 17920);              // 512 f
    float* bh2l = (float*)(smem + 19968);              // 8 f
    float* bh1l = (float*)(smem + 20000);              // 64 f

    int bid = blockIdx.x;
    int t = -1, ci = 0, nt = 0, base = 0;
    {
        int coff = 0, off = 0;
        #pragma unroll 1
        for (int tt = 0; tt < 16; tt++) {
            int c = cnt_g[tt];
            int ch = (c + 63) >> 6;
            if (t < 0 && bid < coff + ch) { t = tt; ci = bid - coff; nt = c; base = off + ci * 64; }
            coff += ch; off += c;
        }
    }
    if (t < 0) return;
    int nvalid = nt - ci * 64; if (nvalid > 64) nvalid = 64;

    int tid = threadIdx.x;
    if (tid < 64) {
        uintx2 rec = {0xFFFFFFFFu, 0u};
        if (tid < nvalid) rec = recs[base + tid];
        toks[tid] = (int)rec[0];
        gats[tid] = __uint_as_float(rec[1]);
    }
    Wh2l[tid] = Wh2[tid];
    Wh2l[tid + 256] = Wh2[tid + 256];
    if (tid < 8) bh2l[tid] = bh2[tid];
    else if (tid < 72) bh1l[tid - 8] = bh1[tid - 8];
    __syncthreads();

    // stage x rows (gathered, zero-padded)
    #pragma unroll
    for (int it = 0; it < 4; it++) {
        int seg = it * 256 + tid; int r = seg >> 4, sg = seg & 15;
        int tk = toks[r];
        uintx4 v = {0u, 0u, 0u, 0u};
        if (tk >= 0) v = *(const uintx4*)(xq + (long)tk * 128 + sg * 8);
        *(uintx4*)(XP + r * 136 + sg * 8) = v;
    }
    __syncthreads();

    int lane = tid & 63, dh = tid >> 6;
    int lane15 = lane & 15, lgrp = lane >> 4;

    // preload all X B-fragments into registers
    short8 xf[4][4];
    #pragma unroll
    for (int kk = 0; kk < 4; kk++)
        #pragma unroll
        for (int mt = 0; mt < 4; mt++)
            xf[kk][mt] = *(const short8*)(XP + (mt * 16 + lane15) * 136 + kk * 32 + lgrp * 8);

    floatx4 acc3[4];
    #pragma unroll
    for (int j = 0; j < 4; j++) acc3[j] = (floatx4){0.f, 0.f, 0.f, 0.f};

    const unsigned short* w1p = W1qT + (long)t * 65536 + lgrp * 8;
    const unsigned short* w23p = W23qT + ((long)t * 64 + dh * 16 + lane15) * 512 + lgrp * 8;

    for (int nc = 0; nc < 4; nc++) {
        __syncthreads();   // nc=0: xf preload reads done; nc>0: prev GEMM2' P reads done

        // GEMM1 + gelu, in two n-halves (A = W1 rows from global, B = xf regs)
        #pragma unroll
        for (int h2 = 0; h2 < 2; h2++) {
            floatx4 acc1[4];
            #pragma unroll
            for (int j = 0; j < 4; j++) acc1[j] = (floatx4){0.f, 0.f, 0.f, 0.f};
            const unsigned short* w1c = w1p + ((long)nc * 16384) + (dh * 32 + h2 * 16 + lane15) * 128;
            #pragma unroll
            for (int kk = 0; kk < 4; kk++) {
                short8 af = *(const short8*)(w1c + kk * 32);
                #pragma unroll
                for (int mt = 0; mt < 4; mt++)
                    acc1[mt] = mfma16(af, xf[kk][mt], acc1[mt]);
            }
            int k2b = dh * 32 + h2 * 16 + lgrp * 4;
            #pragma unroll
            for (int mt = 0; mt < 4; mt++) {
                int m = mt * 16 + lane15;
                floatx4 v = acc1[mt];
                float g0 = gelu_f(v[0]), g1v = gelu_f(v[1]);
                float g2v = gelu_f(v[2]), g3 = gelu_f(v[3]);
                uintx2 o; o[0] = pk2bf(g0, g1v); o[1] = pk2bf(g2v, g3);
                *(uintx2*)(XP + m * 136 + k2b) = o;
            }
        }
        __syncthreads();   // P ready

        // GEMM2': A = W23 rows (global), B = P (LDS), accumulate
        const unsigned short* w23c = w23p + nc * 128;
        #pragma unroll
        for (int kk = 0; kk < 4; kk++) {
            short8 af = *(const short8*)(w23c + kk * 32);
            int ko = kk * 32 + lgrp * 8;
            #pragma unroll
            for (int mt = 0; mt < 4; mt++) {
                short8 bf = *(const short8*)(XP + (mt * 16 + lane15) * 136 + ko);
                acc3[mt] = mfma16(af, bf, acc3[mt]);
            }
        }
    }

    __syncthreads();                         // all GEMM2' reads done; XP free for H
    float* H = (float*)XP;                   // [64 m][68] f32
    int hb = dh * 16 + lgrp * 4;
    floatx4 b4 = *(const floatx4*)(bh1l + hb);
    #pragma unroll
    for (int mt = 0; mt < 4; mt++) {
        int m = mt * 16 + lane15;
        float gm = gats[m];
        floatx4 v;
        v[0] = fmaxf(acc3[mt][0] * gm + b4[0], 0.f);
        v[1] = fmaxf(acc3[mt][1] * gm + b4[1], 0.f);
        v[2] = fmaxf(acc3[mt][2] * gm + b4[2], 0.f);
        v[3] = fmaxf(acc3[mt][3] * gm + b4[3], 0.f);
        *(floatx4*)(H + m * 68 + hb) = v;
    }
    __syncthreads();                         // H complete

    int mloc = tid >> 2, c0 = (tid & 3) * 2;
    int tk = toks[mloc];
    float z0 = bh2l[c0], z1 = bh2l[c0 + 1];
    const floatx4* Hr4 = (const floatx4*)(H + mloc * 68);
    #pragma unroll
    for (int h4 = 0; h4 < 16; h4++) {
        floatx4 hv = Hr4[h4];
        #pragma unroll
        for (int r = 0; r < 4; r++) {
            int h = h4 * 4 + r;
            z0 += hv[r] * Wh2l[h * 8 + c0];
            z1 += hv[r] * Wh2l[h * 8 + c0 + 1];
        }
    }
    if (tk >= 0) {
        float2 rr;
        rr.x = __builtin_amdgcn_rcpf(1.0f + __expf(-z0));
        rr.y = __builtin_amdgcn_rcpf(1.0f + __expf(-z1));
        *(float2*)(result + (long)tk * 8 + c0) = rr;
    }

    // aux loss (block 0 only)
    if (bid == 0 && tid == 0) {
        const float Bf = 262144.0f;
        float tern = ternsum_g[0] * (1.0f / 1048576.0f);
        float sp = 0.f; float cp[4] = {0.f, 0.f, 0.f, 0.f};
        for (int tt = 0; tt < 16; tt++) {
            float frac = (float)cnt_g[tt] / Bf, mp = psum_g[tt] / Bf;
            sp += frac * mp; cp[tt >> 2] += mp;
        }
        float dv = 0.f;
        for (int cc = 0; cc < 4; cc++) dv += cp[cc] * logf(cp[cc] + 1e-9f);
        d_aux[0] = 0.01f * tern + 0.005f * (16.0f * sp) + 0.01f * dv;
    }
}

// ---------------- launch ----------------

extern "C" void kernel_launch(void* const* d_in, const int* in_sizes, int n_in,
                              void* d_out, int out_size, void* d_ws, size_t ws_size,
                              hipStream_t stream) {
    const int* op_idx = (const int*)d_in[0];
    const int* a_in   = (const int*)d_in[1];
    const int* b_in_i = (const int*)d_in[2];
    const int* c_in   = (const int*)d_in[3];
    const float* op_embed = (const float*)d_in[4];
    const float* W_in  = (const float*)d_in[5];
    const float* b_in  = (const float*)d_in[6];
    const float* Wr    = (const float*)d_in[7];
    const float* W1    = (const float*)d_in[8];
    const float* W2    = (const float*)d_in[9];
    const float* Wh1   = (const float*)d_in[10];
    const float* bh1   = (const float*)d_in[11];
    const float* Wh2   = (const float*)d_in[12];
    const float* bh2   = (const float*)d_in[13];

    const long B = in_sizes[0];  // 262144
    float* result = (float*)d_out;
    float* d_idx  = (float*)d_out + B * 8;
    float* d_aux  = (float*)d_out + B * 9;

    unsigned char* ws = (unsigned char*)d_ws;
    unsigned short* xq    = (unsigned short*)(ws + 0);            // 64 MB
    unsigned short* W1qT  = (unsigned short*)(ws + 67108864);     // 2 MB
    unsigned short* W2q   = (unsigned short*)(ws + 69206016);     // 2 MB (untransposed)
    unsigned short* W23qT = (unsigned short*)(ws + 71303168);     // 1 MB
    unsigned short* Wh1T  = (unsigned short*)(ws + 72351744);     // 16 KB
    float* gate   = (float*)(ws + 72368128);                      // 1 MB
    uintx2* records = (uintx2*)(ws + 73416704);                   // 2 MB
    float* Ta    = (float*)(ws + 75513856);                       // 128 KB
    float* Tb    = (float*)(ws + 75644928);                       // 128 KB
    float* embW  = (float*)(ws + 75776000);                       // 4 KB
    float* Tc    = (float*)(ws + 75780096);                       // 512 B
    float* TaR   = (float*)(ws + 75780608);                       // 16 KB
    float* TbR   = (float*)(ws + 75796992);                       // 16 KB
    float* embWr = (float*)(ws + 75813376);                       // 512 B
    float* TcR   = (float*)(ws + 75813888);                       // 64 B
    float* partials = (float*)(ws + 75813952);                    // 2 KB
    unsigned char* acc = ws + 75816000;
    float* ternsum = (float*)(acc + 0);
    float* psum    = (float*)(acc + 64);
    int*   cnt     = (int*)(acc + 128);
    int*   fill    = (int*)(acc + 192);

    hipMemsetAsync(acc, 0, 256, stream);

    k_sumabs<<<512, 256, 0, stream>>>(W1, W2, partials);
    k_quant<<<384, 256, 0, stream>>>(W1, W2, partials, W1qT, W2q, ternsum);
    k_tables<<<293, 256, 0, stream>>>(op_embed, W_in, b_in, Wh1, embW, Ta, Tb, Tc, Wh1T);
    k_tablesR<<<33, 256, 0, stream>>>(embW, Ta, Tb, Tc, Wr, embWr, TaR, TbR, TcR);
    k_front<<<1024, 256, 0, stream>>>(op_idx, a_in, b_in_i, c_in,
                                      embW, Ta, Tb, Tc, embWr, TaR, TbR, TcR,
                                      xq, gate, psum, cnt, d_idx);
    k_w23<<<128, 256, 0, stream>>>(W2q, Wh1T, W23qT);
    k_scatter<<<(int)(B / 256), 256, 0, stream>>>(d_idx, gate, cnt, fill, records);
    k_ffn<<<4112, 256, 20256, stream>>>(xq, records, cnt, psum, ternsum,
                                        W1qT, W23qT, Wh2, bh1, bh2, result, d_aux);
}